// Round 12
// baseline (162.547 us; speedup 1.0000x reference)
//
#include <hip/hip_runtime.h>
#include <hip/hip_fp16.h>

#define BB   8
#define CC   64
#define HH   128
#define WW   128
#define OCC  128
#define HWx  (HH*WW)
#define KTOT 576
#define SST  584    // ushort row stride: 576 + 8 (1168 B, 16B-multiple)

typedef __attribute__((ext_vector_type(8))) short short8t;
typedef __attribute__((ext_vector_type(8))) _Float16 half8t;
typedef __attribute__((ext_vector_type(4))) float f32x4;

static __device__ __forceinline__ ushort f2h(float f) {
    __half h = __float2half_rn(f);
    return __half_as_ushort(h);
}

// ---- K0: conv_w [oc][c*9+tap] fp32 -> wb [oc][tap*64+c] fp16 --------------
__global__ __launch_bounds__(256) void kprep(const float* __restrict__ w,
                                             ushort* __restrict__ wb) {
    int i = blockIdx.x * 256 + threadIdx.x;   // 73728
    int oc = i / KTOT, k = i - oc * KTOT;
    int c = k / 9, tap = k - c * 9;
    wb[oc * KTOT + tap * 64 + c] = f2h(w[i]);
}

// ---- K0c: off_w [ch][c*9+tap] -> wT [(c*9+tap)*18 + ch] fp32 --------------
__global__ __launch_bounds__(256) void kprepw(const float* __restrict__ ow,
                                              float* __restrict__ wT) {
    int i = blockIdx.x * 256 + threadIdx.x;   // 18*576 = 10368
    if (i < 18 * KTOT) {
        int ch = i / KTOT, r = i - ch * KTOT;
        wT[r * 18 + ch] = ow[i];
    }
}

// ---- K0b: x NCHW fp32 -> xT NHWC fp16, direct -----------------------------
__global__ __launch_bounds__(256) void ktrans(const float* __restrict__ x,
                                              ushort* __restrict__ xT) {
    int tid = threadIdx.x;
    int b   = blockIdx.x >> 8;
    int p   = (blockIdx.x & 255) * 64 + (tid & 63);
    int cg  = tid >> 6;                  // 0..3 -> channels cg*16..+15
    const float* xb = x + (size_t)b * CC * HWx + p;
    ushort* ob = xT + ((size_t)b * HWx + p) * 64 + cg * 16;
    short8t v0, v1;
#pragma unroll
    for (int e = 0; e < 8; ++e) v0[e] = (short)f2h(xb[(size_t)(cg * 16 + e) * HWx]);
#pragma unroll
    for (int e = 0; e < 8; ++e) v1[e] = (short)f2h(xb[(size_t)(cg * 16 + 8 + e) * HWx]);
    *(short8t*)ob = v0;
    *(short8t*)(ob + 8) = v1;
}

// ---- K1: offset conv (ch 0..17), fp32 exact, LDS-free ---------------------
__global__ __launch_bounds__(256) void koff5(const float* __restrict__ x,
                                             const float* __restrict__ wT,
                                             const float* __restrict__ off_b,
                                             float* __restrict__ offsT) {
    int tid = threadIdx.x;
    int b = blockIdx.x & 7;
    int i = blockIdx.x >> 3;
    int g9 = __builtin_amdgcn_readfirstlane((tid >> 7) * 9);  // wave-uniform
    int j = tid & 127;
    const float* xb = x + (size_t)b * CC * HWx;

    float acc[9];
#pragma unroll
    for (int u = 0; u < 9; ++u) acc[u] = off_b[g9 + u];

    for (int c = 0; c < CC; ++c) {
        const float* xc = xb + (size_t)c * HWx;
#pragma unroll
        for (int di = 0; di < 3; ++di) {
            int r = i + di - 1;
            bool rv = (r >= 0) && (r < HH);
#pragma unroll
            for (int dj = 0; dj < 3; ++dj) {
                int s = j + dj - 1;
                float xv = (rv && s >= 0 && s < WW) ? xc[r * WW + s] : 0.f;
                const float* wrow = &wT[(c * 9 + di * 3 + dj) * 18 + g9];
#pragma unroll
                for (int u = 0; u < 9; ++u)
                    acc[u] = fmaf(xv, wrow[u], acc[u]);
            }
        }
    }
    float* ob = offsT + ((size_t)(b * HWx) + i * WW + j) * 18 + g9;
#pragma unroll
    for (int u = 0; u < 9; ++u) ob[u] = acc[u];
}

// ---- per-chain macros for kmain phase 1 (named regs, depth-4 pipeline) ----
#define CHAIN_DECODE(q, SS) \
    const int s##q = (SS); \
    const int pix##q = s##q / 72; \
    const int rr##q = s##q - pix##q * 72; \
    const int tap##q = rr##q >> 3; \
    const int cg##q = rr##q & 7; \
    const int kr##q = tap##q / 3, kc##q = tap##q - kr##q * 3; \
    const int si##q = oi + ((kr##q == 0) ? -1 : 0); \
    const int sj##q = oj0 + pix##q + ((kc##q == 0) ? -1 : 0); \
    const bool v##q = (si##q >= 0) && (sj##q >= 0); \
    const int n##q = ((kr##q == 0) ? 2 : kr##q - 1) * 3 + ((kc##q == 0) ? 2 : kc##q - 1); \
    const int pidx##q = v##q ? (si##q * WW + sj##q) : 0; \
    const float ox##q = offb[pidx##q * 18 + n##q]; \
    const float oy##q = offb[pidx##q * 18 + 9 + n##q];

#define CHAIN_ADDR(q) \
    float px##q = (float)si##q + ox##q; \
    float py##q = (float)sj##q + oy##q; \
    float fx##q = floorf(px##q), fy##q = floorf(py##q); \
    float pxc##q   = fminf(fmaxf(px##q, 0.f), 127.f); \
    float pyc##q   = fminf(fmaxf(py##q, 0.f), 127.f); \
    float qltxf##q = fminf(fmaxf(fx##q, 0.f), 127.f); \
    float qltyf##q = fminf(fmaxf(fy##q, 0.f), 127.f); \
    float qrbxf##q = fminf(fmaxf(fx##q + 1.f, 0.f), 127.f); \
    float qrbyf##q = fminf(fmaxf(fy##q + 1.f, 0.f), 127.f); \
    int qltx##q = (int)qltxf##q, qlty##q = (int)qltyf##q; \
    int qrbx##q = (int)qrbxf##q, qrby##q = (int)qrbyf##q; \
    const int co##q = cg##q * 8; \
    uint4 lt##q = *(const uint4*)(xTb + (size_t)(qltx##q * WW + qlty##q) * 64 + co##q); \
    uint4 rb##q = *(const uint4*)(xTb + (size_t)(qrbx##q * WW + qrby##q) * 64 + co##q); \
    uint4 lb##q = *(const uint4*)(xTb + (size_t)(qltx##q * WW + qrby##q) * 64 + co##q); \
    uint4 rt##q = *(const uint4*)(xTb + (size_t)(qrbx##q * WW + qlty##q) * 64 + co##q); \
    float glt##q = (1.f + (qltxf##q - pxc##q)) * (1.f + (qltyf##q - pyc##q)); \
    float grb##q = (1.f - (qrbxf##q - pxc##q)) * (1.f - (qrbyf##q - pyc##q)); \
    float glb##q = (1.f + (qltxf##q - pxc##q)) * (1.f - (qrbyf##q - pyc##q)); \
    float grt##q = (1.f - (qrbxf##q - pxc##q)) * (1.f + (qltyf##q - pyc##q));

#define LERP1(q, comp) \
    a = __hmul2(hlt, __builtin_bit_cast(__half2, lt##q.comp)); \
    a = __hfma2(hrb, __builtin_bit_cast(__half2, rb##q.comp), a); \
    a = __hfma2(hlb, __builtin_bit_cast(__half2, lb##q.comp), a); \
    a = __hfma2(hrt, __builtin_bit_cast(__half2, rt##q.comp), a);

#define CHAIN_FINISH(q) { \
    __half2 hlt = __float2half2_rn(glt##q); \
    __half2 hrb = __float2half2_rn(grb##q); \
    __half2 hlb = __float2half2_rn(glb##q); \
    __half2 hrt = __float2half2_rn(grt##q); \
    uint4 o; __half2 a; \
    LERP1(q, x) o.x = __builtin_bit_cast(uint, a); \
    LERP1(q, y) o.y = __builtin_bit_cast(uint, a); \
    LERP1(q, z) o.z = __builtin_bit_cast(uint, a); \
    LERP1(q, w) o.w = __builtin_bit_cast(uint, a); \
    if (!v##q) { o.x = 0u; o.y = 0u; o.z = 0u; o.w = 0u; } \
    *(uint4*)(&S[pix##q * SST + tap##q * 64 + cg##q * 8]) = o; }

// ---- K2: fused packed-fp16 gather + MFMA, depth-4 pipelined phase 1 --------
// Block: 512 thr (8 waves), 32 pixels x 128 oc. grid = 4096, b = bi&7.
__global__ __launch_bounds__(512, 4) void kmain12(const ushort* __restrict__ xT,
                                                  const float* __restrict__ offsT,
                                                  const ushort* __restrict__ wb,
                                                  const float* __restrict__ conv_b,
                                                  float* __restrict__ out) {
    __shared__ __align__(16) ushort S[32 * SST];   // 37376 B (fp16 bits)
    int tid = threadIdx.x;                 // 0..511
    int bi  = blockIdx.x;
    int b   = bi & 7;                      // XCD-affine batch
    int rem = bi >> 3;
    int oi  = rem >> 2;
    int oj0 = (rem & 3) * 32;

    const ushort* xTb  = xT + (size_t)b * HWx * 64;
    const float*  offb = offsT + (size_t)b * HWx * 18;

    // ---- phase 2 setup + ks=0 weight prefetch (independent of S) ----
    int wv = tid >> 6;                     // wave 0..7: oc tile [16wv,16wv+16)
    int l  = tid & 63;
    int lr = l & 15;
    int lg = l >> 4;
    const ushort* wr0 = wb + (size_t)(16 * wv + lr) * KTOT + lg * 8;
    half8t pa0 = *(const half8t*)(wr0);

    // ---- phase 1: 2304 subtasks; depth-4 pipeline + 256-thread tail ----
    {
        CHAIN_DECODE(0, tid)
        CHAIN_DECODE(1, tid + 512)
        CHAIN_DECODE(2, tid + 1024)
        CHAIN_DECODE(3, tid + 1536)
        CHAIN_ADDR(0)
        CHAIN_ADDR(1)
        CHAIN_ADDR(2)
        CHAIN_ADDR(3)
        CHAIN_FINISH(0)
        CHAIN_FINISH(1)
        CHAIN_FINISH(2)
        CHAIN_FINISH(3)
    }
    if (tid < 256) {
        CHAIN_DECODE(4, tid + 2048)
        CHAIN_ADDR(4)
        CHAIN_FINISH(4)
    }
    __syncthreads();

    // ---- phase 2: 128oc x 32pix x 576K GEMM (16x16x32 fp16 MFMA) ----
    f32x4 acc[2];                          // [pix tile 0/1]
#pragma unroll
    for (int e = 0; e < 4; ++e) {
        float bv = conv_b[16 * wv + lg * 4 + e];
        acc[0][e] = bv;
        acc[1][e] = bv;
    }
    const ushort* s0 = &S[(lr) * SST + lg * 8];
    const ushort* s1 = &S[(16 + lr) * SST + lg * 8];

#pragma unroll 3
    for (int ks = 0; ks < 18; ++ks) {
        int kk = ks * 32;
        half8t a0 = (ks == 0) ? pa0 : *(const half8t*)(wr0 + kk);
        half8t b0 = *(const half8t*)(s0 + kk);
        half8t b1 = *(const half8t*)(s1 + kk);
        acc[0] = __builtin_amdgcn_mfma_f32_16x16x32_f16(a0, b0, acc[0], 0, 0, 0);
        acc[1] = __builtin_amdgcn_mfma_f32_16x16x32_f16(a0, b1, acc[1], 0, 0, 0);
    }

    float* ob = out + ((size_t)b * OCC * HH + oi) * WW + oj0;
#pragma unroll
    for (int p = 0; p < 2; ++p) {
#pragma unroll
        for (int e = 0; e < 4; ++e) {
            int oc  = 16 * wv + lg * 4 + e;
            int col = 16 * p + lr;
            ob[(size_t)oc * HWx + col] = acc[p][e];
        }
    }
}

extern "C" void kernel_launch(void* const* d_in, const int* in_sizes, int n_in,
                              void* d_out, int out_size, void* d_ws, size_t ws_size,
                              hipStream_t stream) {
    const float* x      = (const float*)d_in[0];
    const float* off_w  = (const float*)d_in[1];
    const float* off_b  = (const float*)d_in[2];
    const float* conv_w = (const float*)d_in[3];
    const float* conv_b = (const float*)d_in[4];
    float* out = (float*)d_out;

    ushort* wbf   = (ushort*)d_ws;                              // 147456 B
    float*  offsT = (float*)((char*)d_ws + 147456);             // 9.44 MB
    ushort* xT    = (ushort*)((char*)d_ws + 147456 + 9437184);  // 16.78 MB
    float*  wT    = (float*)((char*)d_ws + 147456 + 9437184 + 16777216); // 41.5 KB

    kprep<<<(OCC * KTOT) / 256, 256, 0, stream>>>(conv_w, wbf);
    kprepw<<<41, 256, 0, stream>>>(off_w, wT);
    ktrans<<<BB * (HWx / 64), 256, 0, stream>>>(x, xT);
    koff5<<<BB * HH, 256, 0, stream>>>(x, wT, off_b, offsT);
    kmain12<<<BB * HH * 4, 512, 0, stream>>>(xT, offsT, wbf, conv_b, out);
}